// Round 1
// baseline (217.403 us; speedup 1.0000x reference)
//
#include <hip/hip_runtime.h>

// STDP learner: tr_pre/tr_post elementwise + delta_w = 0.5*w*(conv-wgrad pair).
// delta_w[o,i,kh,kw] = 0.5*w[o,i,kh,kw] *
//   sum_{b,p,q} trace_pre[b,i,p+kh,q+kw]*out_spike[b,o,p,q]
//             - trace_post[b,o,p,q]*in_spike[b,i,p+kh,q+kw]
// (the in_sh*out cross terms cancel exactly vs the reference formulation)
//
// Sizes: B=16 CIN=64 H=W=66 COUT=128 HO=WO=64 KH=KW=3
// out layout: [tr_pre 4460544][tr_post 8388608][delta_w 73728]

typedef unsigned short ushort_t;
typedef unsigned int uint_t;
typedef __attribute__((ext_vector_type(8))) short short8;
typedef __attribute__((ext_vector_type(4))) float floatx4;

#define N_PRE   4460544      // 16*64*66*66
#define N_POST  8388608      // 16*128*64*64
#define N_DW    73728        // 128*64*9
#define O_TRPOST 4460544
#define O_DW     12849152
#define BSLICE   4325376     // per-kw shifted B copy: 16*64*66*64 elems

__device__ __forceinline__ ushort_t f2bf(float f) {
  uint_t u = __builtin_bit_cast(uint_t, f);
  u = (u + 0x7FFFu + ((u >> 16) & 1u)) >> 16;   // RNE
  return (ushort_t)u;
}

// ---- elementwise tr_pre + bf16 shifted B copies ----------------------------
__global__ void k_pre(const float* __restrict__ in_sp, const float* __restrict__ tpre,
                      float* __restrict__ o_trpre,
                      ushort_t* __restrict__ B1, ushort_t* __restrict__ B2, int write_ws) {
  int idx = blockIdx.x * 256 + threadIdx.x;            // exact grid: N_PRE/256
  float tp = tpre[idx], is = in_sp[idx];
  o_trpre[idx] = 0.5f * tp + is;
  if (write_ws) {
    int row = idx / 66;                                 // (b*64+i)*66 + h
    int q66 = idx - row * 66;
    ushort_t tpb = f2bf(tp), isb = f2bf(is);
    #pragma unroll
    for (int kw = 0; kw < 3; ++kw) {
      int q = q66 - kw;
      if (q >= 0 && q < 64) {
        B1[kw * BSLICE + row * 64 + q] = tpb;           // trace_pre shifted
        B2[kw * BSLICE + row * 64 + q] = isb;           // in_spike shifted
      }
    }
  }
}

// ---- elementwise tr_post + bf16 A copies -----------------------------------
__global__ void k_post(const float* __restrict__ out_sp, const float* __restrict__ tpost,
                       float* __restrict__ o_trpost,
                       ushort_t* __restrict__ A1, ushort_t* __restrict__ A2, int write_ws) {
  int idx = blockIdx.x * 256 + threadIdx.x;            // exact grid: N_POST/256
  float tp = tpost[idx], os = out_sp[idx];
  o_trpost[idx] = 0.5f * tp + os;
  if (write_ws) {
    A1[idx] = f2bf(os);                                 // out_spike
    A2[idx] = f2bf(-tp);                                // -trace_post (negation folded)
  }
}

// ---- main MFMA split-K kernel ----------------------------------------------
// grid (64, 9): x = k-chunk (16 rows of (b,p)), y = offset e = kh*3+kw
// block 256 = 4 waves; wave w computes o in [w*32,w*32+32) x all 64 i.
__global__ __launch_bounds__(256, 2)
void k_mfma(const ushort_t* __restrict__ A1, const ushort_t* __restrict__ A2,
            const ushort_t* __restrict__ B1, const ushort_t* __restrict__ B2,
            float* __restrict__ partials) {
  // +72 stride (not 64): 144B row stride -> 16B aligned, breaks 32-bank aliasing
  __shared__ short LA[2][128][72];   // 36,864 B
  __shared__ short LB[2][64][72];    // 18,432 B  (total 55,296 B -> 2 blocks/CU)

  const int e = blockIdx.y, kh = e / 3, kw = e - kh * 3;
  const ushort_t* B1e = B1 + kw * BSLICE;
  const ushort_t* B2e = B2 + kw * BSLICE;
  const int t = threadIdx.x, wave = t >> 6, lane = t & 63;
  const int quad = lane >> 4, l16 = lane & 15;

  floatx4 acc[2][4] = {};   // both terms share accumulators (A2 pre-negated)

  for (int rr = 0; rr < 16; ++rr) {
    const int r = blockIdx.x * 16 + rr;                // row index over (b,p)
    const int b = r >> 6, p = r & 63;

    // stage A rows: 2 mats x 128 o x 8 chunks(16B) = 2048 chunks, 8/thread
    const long baseA = (long)b * 524288 + p * 64;      // [b][o][p][q], o stride 4096
    #pragma unroll
    for (int it = 0; it < 4; ++it) {
      int c = t + it * 256;                            // 0..1023
      int o = c >> 3, s = c & 7;
      *(short8*)&LA[0][o][s * 8] = *(const short8*)(A1 + baseA + o * 4096 + s * 8);
      *(short8*)&LA[1][o][s * 8] = *(const short8*)(A2 + baseA + o * 4096 + s * 8);
    }
    // stage B rows (pre-shifted copies, aligned): 2 x 64 x 8 chunks, 4/thread
    const long baseB = (long)b * 270336 + (p + kh) * 64;  // [b][i][h][64], i stride 4224
    #pragma unroll
    for (int it = 0; it < 2; ++it) {
      int c = t + it * 256;                            // 0..511
      int i = c >> 3, s = c & 7;
      *(short8*)&LB[0][i][s * 8] = *(const short8*)(B1e + baseB + i * 4224 + s * 8);
      *(short8*)&LB[1][i][s * 8] = *(const short8*)(B2e + baseB + i * 4224 + s * 8);
    }
    __syncthreads();

    const int ob = wave * 32;
    #pragma unroll
    for (int ks = 0; ks < 2; ++ks) {
      const int col = ks * 32 + quad * 8;              // k = col + j, j=0..7
      // A-operand layout: A[m=lane&15][k=quad*8+j]  (HW-verified m120)
      short8 a00 = *(const short8*)&LA[0][ob + l16][col];
      short8 a01 = *(const short8*)&LA[0][ob + 16 + l16][col];
      short8 a10 = *(const short8*)&LA[1][ob + l16][col];
      short8 a11 = *(const short8*)&LA[1][ob + 16 + l16][col];
      #pragma unroll
      for (int nt = 0; nt < 4; ++nt) {
        short8 b0 = *(const short8*)&LB[0][nt * 16 + l16][col];
        short8 b1 = *(const short8*)&LB[1][nt * 16 + l16][col];
        acc[0][nt] = __builtin_amdgcn_mfma_f32_16x16x32_bf16(a00, b0, acc[0][nt], 0, 0, 0);
        acc[0][nt] = __builtin_amdgcn_mfma_f32_16x16x32_bf16(a10, b1, acc[0][nt], 0, 0, 0);
        acc[1][nt] = __builtin_amdgcn_mfma_f32_16x16x32_bf16(a01, b0, acc[1][nt], 0, 0, 0);
        acc[1][nt] = __builtin_amdgcn_mfma_f32_16x16x32_bf16(a11, b1, acc[1][nt], 0, 0, 0);
      }
    }
    __syncthreads();
  }

  // epilogue: C/D layout col(i)=lane&15, row(o within 16)=quad*4+reg (m89/m91)
  float* slice = partials + ((size_t)(e * 64 + blockIdx.x) * 8192);
  #pragma unroll
  for (int mt = 0; mt < 2; ++mt)
    #pragma unroll
    for (int nt = 0; nt < 4; ++nt)
      #pragma unroll
      for (int rg = 0; rg < 4; ++rg) {
        int o = wave * 32 + mt * 16 + quad * 4 + rg;
        int i = nt * 16 + l16;
        slice[o * 64 + i] = acc[mt][nt][rg];
      }
}

// ---- split-K reduction + finalize ------------------------------------------
__global__ void k_finalize(const float* __restrict__ partials,
                           const float* __restrict__ weight, float* __restrict__ dw) {
  int tid = blockIdx.x * 256 + threadIdx.x;            // < 73728
  int e = tid >> 13, oi = tid & 8191;
  float s = 0.f;
  #pragma unroll 8
  for (int c = 0; c < 64; ++c) s += partials[(size_t)(e * 64 + c) * 8192 + oi];
  int o = oi >> 6, i = oi & 63;
  int kh = e / 3, kw = e - kh * 3;
  int wi = (o * 64 + i) * 9 + kh * 3 + kw;
  dw[wi] = 0.5f * weight[wi] * s;
}

// ---- fallback (ws too small): slow fp32, zero scratch ----------------------
__global__ void k_naive(const float* __restrict__ out_sp, const float* __restrict__ tpost,
                        const float* __restrict__ tpre, const float* __restrict__ in_sp,
                        const float* __restrict__ weight, float* __restrict__ dw) {
  int tid = blockIdx.x * 256 + threadIdx.x;
  int e = tid >> 13, oi = tid & 8191;
  int o = oi >> 6, i = oi & 63;
  int kh = e / 3, kw = e - kh * 3;
  float acc = 0.f;
  for (int b = 0; b < 16; ++b)
    for (int p = 0; p < 64; ++p) {
      const float* ga = out_sp + ((b * 128 + o) * 64 + p) * 64;
      const float* gn = tpost + ((b * 128 + o) * 64 + p) * 64;
      const float* gb = tpre + ((b * 64 + i) * 66 + p + kh) * 66 + kw;
      const float* gm = in_sp + ((b * 64 + i) * 66 + p + kh) * 66 + kw;
      for (int q = 0; q < 64; ++q) acc += ga[q] * gb[q] - gn[q] * gm[q];
    }
  int wi = (o * 64 + i) * 9 + kh * 3 + kw;
  dw[wi] = 0.5f * weight[wi] * acc;
}

extern "C" void kernel_launch(void* const* d_in, const int* in_sizes, int n_in,
                              void* d_out, int out_size, void* d_ws, size_t ws_size,
                              hipStream_t stream) {
  const float* in_sp  = (const float*)d_in[0];
  const float* out_sp = (const float*)d_in[1];
  const float* tpre   = (const float*)d_in[2];
  const float* tpost  = (const float*)d_in[3];
  const float* weight = (const float*)d_in[4];
  float* out = (float*)d_out;
  float* o_trpre  = out;
  float* o_trpost = out + O_TRPOST;
  float* o_dw     = out + O_DW;

  // ws layout (bytes): A1 16.78M | A2 16.78M | B1 25.95M | B2 25.95M | partials 18.87M
  const size_t WS_NEED = 104333312;
  const int use_mfma = (ws_size >= WS_NEED) ? 1 : 0;
  ushort_t* A1 = (ushort_t*)d_ws;
  ushort_t* A2 = A1 + 8388608;
  ushort_t* B1 = A2 + 8388608;
  ushort_t* B2 = B1 + 3 * BSLICE;
  float* partials = (float*)(B2 + 3 * BSLICE);

  k_pre <<<N_PRE  / 256, 256, 0, stream>>>(in_sp, tpre, o_trpre, B1, B2, use_mfma);
  k_post<<<N_POST / 256, 256, 0, stream>>>(out_sp, tpost, o_trpost, A1, A2, use_mfma);
  if (use_mfma) {
    dim3 g(64, 9);
    k_mfma<<<g, 256, 0, stream>>>(A1, A2, B1, B2, partials);
    k_finalize<<<N_DW / 256, 256, 0, stream>>>(partials, weight, o_dw);
  } else {
    k_naive<<<N_DW / 256, 256, 0, stream>>>(out_sp, tpost, tpre, in_sp, weight, o_dw);
  }
}

// Round 2
// 216.082 us; speedup vs baseline: 1.0061x; 1.0061x over previous
//
#include <hip/hip_runtime.h>

// STDP learner: tr_pre/tr_post elementwise + delta_w = 0.5*w*(conv-wgrad pair).
// delta_w[o,i,kh,kw] = 0.5*w[o,i,kh,kw] *
//   sum_{b,p,q} tpre[b,i,p+kh,q+kw]*out[b,o,p,q] - tpost[b,o,p,q]*in[b,i,p+kh,q+kw]
// Sizes: B=16 CIN=64 H=W=66 COUT=128 HO=WO=64 KH=KW=3
// out layout: [tr_pre 4460544][tr_post 8388608][delta_w 73728]

typedef unsigned short ushort_t;
typedef unsigned int uint_t;
typedef __attribute__((ext_vector_type(8))) short short8;
typedef __attribute__((ext_vector_type(4))) float floatx4;
typedef __attribute__((ext_vector_type(2))) float floatx2;

#define N_PRE   4460544      // 16*64*66*66
#define N_POST  8388608      // 16*128*64*64
#define N_DW    73728        // 128*64*9
#define O_TRPOST 4460544
#define O_DW     12849152
#define BSLICE   4325376     // per-kw shifted B copy: 16*64*66*64 elems

// async global->LDS, 16B/lane; LDS dst = wave-uniform base + lane*16
#define GLDS16(g, l) __builtin_amdgcn_global_load_lds( \
    (const __attribute__((address_space(1))) void*)(g), \
    (__attribute__((address_space(3))) void*)(l), 16, 0, 0)

__device__ __forceinline__ ushort_t f2bf(float f) {
  uint_t u = __builtin_bit_cast(uint_t, f);
  u = (u + 0x7FFFu + ((u >> 16) & 1u)) >> 16;   // RNE
  return (ushort_t)u;
}

// ---- pure elementwise tr_pre (float4) --------------------------------------
__global__ void k_pre_elem(const float* __restrict__ in_sp, const float* __restrict__ tpre,
                           float* __restrict__ o_trpre) {
  int t4 = (blockIdx.x * 256 + threadIdx.x) * 4;       // exact: N_PRE/4 threads
  floatx4 tp = *(const floatx4*)(tpre + t4);
  floatx4 is = *(const floatx4*)(in_sp + t4);
  *(floatx4*)(o_trpre + t4) = 0.5f * tp + is;
}

// ---- bf16 shifted B slices, aligned 16B stores -----------------------------
// thread = (row, q8): row = (b*64+i)*66+h over 67584 rows, q8 = 8-col group
__global__ void k_bfill(const float* __restrict__ in_sp, const float* __restrict__ tpre,
                        ushort_t* __restrict__ B1, ushort_t* __restrict__ B2) {
  int tid = blockIdx.x * 256 + threadIdx.x;            // exact: 540672 threads
  int row = tid >> 3, q8 = (tid & 7) * 8;
  int g = row * 66 + q8;                               // even -> float2 aligned
  float ftp[10], fin[10];
  #pragma unroll
  for (int k = 0; k < 5; ++k) {
    floatx2 a = *(const floatx2*)(tpre + g + 2 * k);
    floatx2 b = *(const floatx2*)(in_sp + g + 2 * k);
    ftp[2 * k] = a.x; ftp[2 * k + 1] = a.y;
    fin[2 * k] = b.x; fin[2 * k + 1] = b.y;
  }
  ushort_t utp[10], uin[10];
  #pragma unroll
  for (int k = 0; k < 10; ++k) { utp[k] = f2bf(ftp[k]); uin[k] = f2bf(fin[k]); }
  int dst = row * 64 + q8;                             // byte offset 16-aligned
  #pragma unroll
  for (int kw = 0; kw < 3; ++kw) {
    short8 v1, v2;
    #pragma unroll
    for (int k = 0; k < 8; ++k) { v1[k] = (short)utp[kw + k]; v2[k] = (short)uin[kw + k]; }
    *(short8*)(B1 + kw * BSLICE + dst) = v1;
    *(short8*)(B2 + kw * BSLICE + dst) = v2;
  }
}

// ---- elementwise tr_post + bf16 A copies (float4 + 16B stores) -------------
__global__ void k_post(const float* __restrict__ out_sp, const float* __restrict__ tpost,
                       float* __restrict__ o_trpost,
                       ushort_t* __restrict__ A1, ushort_t* __restrict__ A2, int write_ws) {
  int t8 = (blockIdx.x * 256 + threadIdx.x) * 8;       // exact: N_POST/8 threads
  floatx4 o0 = *(const floatx4*)(out_sp + t8);
  floatx4 o1 = *(const floatx4*)(out_sp + t8 + 4);
  floatx4 p0 = *(const floatx4*)(tpost + t8);
  floatx4 p1 = *(const floatx4*)(tpost + t8 + 4);
  *(floatx4*)(o_trpost + t8)     = 0.5f * p0 + o0;
  *(floatx4*)(o_trpost + t8 + 4) = 0.5f * p1 + o1;
  if (write_ws) {
    short8 va, vn;
    #pragma unroll
    for (int k = 0; k < 4; ++k) {
      va[k] = (short)f2bf(o0[k]); va[k + 4] = (short)f2bf(o1[k]);
      vn[k] = (short)f2bf(-p0[k]); vn[k + 4] = (short)f2bf(-p1[k]);
    }
    *(short8*)(A1 + t8) = va;
    *(short8*)(A2 + t8) = vn;
  }
}

// ---- main MFMA split-K kernel ----------------------------------------------
// grid (64, 2, 9): x = k-chunk (16 (b,p) rows), y = o-half, z = e = kh*3+kw
// block 128 = 2 waves; wave w covers o_local in [w*32, w*32+32) x all 64 i.
// LDS linear (global_load_lds requires it); bank conflicts broken by XOR
// swizzle s^(row&7) applied to the GLOBAL source chunk per LDS slot.
__global__ __launch_bounds__(128, 3)
void k_mfma(const ushort_t* __restrict__ A1, const ushort_t* __restrict__ A2,
            const ushort_t* __restrict__ B1, const ushort_t* __restrict__ B2,
            float* __restrict__ partials) {
  __shared__ short LA[8192];   // 2 mats x 64 o x 8 chunks x 8 shorts = 16 KB
  __shared__ short LB[8192];   // 2 mats x 64 i x 8 chunks           = 16 KB

  const int oh = blockIdx.y, e = blockIdx.z;
  const int kh = e / 3, kw = e - kh * 3;
  const int t = threadIdx.x, w = t >> 6, l = t & 63;
  const int quad = l >> 4, l16 = l & 15;
  const int wo = w * 32;

  // staging decode: instr j, lane l -> row j*8+(l>>3), slot l&7,
  // source chunk s = (l&7) ^ (row&7) = (l&7) ^ ((l>>3)&7)  (j*8 drops out)
  const int lrow = l >> 3;
  const int s_sw = (l & 7) ^ (lrow & 7);
  const int aoff_lane = lrow * 4096 + s_sw * 8;        // A o-stride 4096 elems
  const int boff_lane = lrow * 4224 + s_sw * 8;        // B i-stride 4224 elems

  const ushort_t* PA = (w == 0) ? A1 : A2;             // wave w stages mat w
  const ushort_t* PB = ((w == 0) ? B1 : B2) + kw * BSLICE;
  short* la = LA + w * 4096;
  short* lb = LB + w * 4096;

  floatx4 acc[2][4] = {};

  for (int rr = 0; rr < 16; ++rr) {
    const int r = blockIdx.x * 16 + rr;                // (b,p) row index
    const int b = r >> 6, p = r & 63;
    const ushort_t* ga = PA + b * 524288 + oh * 262144 + p * 64 + aoff_lane;
    const ushort_t* gb = PB + b * 270336 + (p + kh) * 64 + boff_lane;

    __syncthreads();                                   // prev compute done
    #pragma unroll
    for (int j = 0; j < 8; ++j) {
      GLDS16(ga + j * 32768, la + j * 512);            // 8 o-rows x 8 chunks / instr
      GLDS16(gb + j * 33792, lb + j * 512);
    }
    __syncthreads();                                   // drains vmcnt -> LDS valid

    #pragma unroll
    for (int ks = 0; ks < 2; ++ks) {
      const int s0 = ks * 4 + quad;
      const int o0 = wo + l16, o1 = wo + 16 + l16;
      const int ca0 = (o0 * 8 + (s0 ^ (o0 & 7))) * 8;
      const int ca1 = (o1 * 8 + (s0 ^ (o1 & 7))) * 8;
      short8 a00 = *(const short8*)&LA[ca0];
      short8 a10 = *(const short8*)&LA[4096 + ca0];
      short8 a01 = *(const short8*)&LA[ca1];
      short8 a11 = *(const short8*)&LA[4096 + ca1];
      #pragma unroll
      for (int nt = 0; nt < 4; ++nt) {
        const int i = nt * 16 + l16;
        const int cb = (i * 8 + (s0 ^ (i & 7))) * 8;
        short8 b0 = *(const short8*)&LB[cb];
        short8 b1 = *(const short8*)&LB[4096 + cb];
        acc[0][nt] = __builtin_amdgcn_mfma_f32_16x16x32_bf16(a00, b0, acc[0][nt], 0, 0, 0);
        acc[0][nt] = __builtin_amdgcn_mfma_f32_16x16x32_bf16(a10, b1, acc[0][nt], 0, 0, 0);
        acc[1][nt] = __builtin_amdgcn_mfma_f32_16x16x32_bf16(a01, b0, acc[1][nt], 0, 0, 0);
        acc[1][nt] = __builtin_amdgcn_mfma_f32_16x16x32_bf16(a11, b1, acc[1][nt], 0, 0, 0);
      }
    }
  }

  // C/D layout: col(i)=lane&15, row(o within 16)=quad*4+reg (HW-verified)
  float* slice = partials + (size_t)((e * 64 + blockIdx.x) * 2 + oh) * 4096;
  #pragma unroll
  for (int mt = 0; mt < 2; ++mt)
    #pragma unroll
    for (int nt = 0; nt < 4; ++nt)
      #pragma unroll
      for (int rg = 0; rg < 4; ++rg) {
        int o = wo + mt * 16 + quad * 4 + rg;
        int i = nt * 16 + l16;
        slice[o * 64 + i] = acc[mt][nt][rg];
      }
}

// ---- split-K reduction + finalize ------------------------------------------
__global__ void k_finalize(const float* __restrict__ partials,
                           const float* __restrict__ weight, float* __restrict__ dw) {
  int tid = blockIdx.x * 256 + threadIdx.x;            // < 73728
  int e = tid >> 13, oi = tid & 8191;
  int o = oi >> 6, i = oi & 63;
  int ohh = o >> 6, ol = o & 63;
  const float* pp = partials + (size_t)e * 524288 + ohh * 4096 + ol * 64 + i;
  float s = 0.f;
  #pragma unroll 8
  for (int x = 0; x < 64; ++x) s += pp[x * 8192];
  int wi = (o * 64 + i) * 9 + e;
  dw[wi] = 0.5f * weight[wi] * s;
}

// ---- fallback (ws too small): slow fp32, zero scratch ----------------------
__global__ void k_naive(const float* __restrict__ out_sp, const float* __restrict__ tpost,
                        const float* __restrict__ tpre, const float* __restrict__ in_sp,
                        const float* __restrict__ weight, float* __restrict__ dw) {
  int tid = blockIdx.x * 256 + threadIdx.x;
  int e = tid >> 13, oi = tid & 8191;
  int o = oi >> 6, i = oi & 63;
  int kh = e / 3, kw = e - kh * 3;
  float acc = 0.f;
  for (int b = 0; b < 16; ++b)
    for (int p = 0; p < 64; ++p) {
      const float* ga = out_sp + ((b * 128 + o) * 64 + p) * 64;
      const float* gn = tpost + ((b * 128 + o) * 64 + p) * 64;
      const float* gb = tpre + ((b * 64 + i) * 66 + p + kh) * 66 + kw;
      const float* gm = in_sp + ((b * 64 + i) * 66 + p + kh) * 66 + kw;
      for (int q = 0; q < 64; ++q) acc += ga[q] * gb[q] - gn[q] * gm[q];
    }
  int wi = (o * 64 + i) * 9 + kh * 3 + kw;
  dw[wi] = 0.5f * weight[wi] * acc;
}

extern "C" void kernel_launch(void* const* d_in, const int* in_sizes, int n_in,
                              void* d_out, int out_size, void* d_ws, size_t ws_size,
                              hipStream_t stream) {
  const float* in_sp  = (const float*)d_in[0];
  const float* out_sp = (const float*)d_in[1];
  const float* tpre   = (const float*)d_in[2];
  const float* tpost  = (const float*)d_in[3];
  const float* weight = (const float*)d_in[4];
  float* out = (float*)d_out;
  float* o_trpre  = out;
  float* o_trpost = out + O_TRPOST;
  float* o_dw     = out + O_DW;

  // ws layout: A1 | A2 | B1(3 slices) | B2(3 slices) | partials
  const size_t WS_NEED = 104333312;
  const int use_mfma = (ws_size >= WS_NEED) ? 1 : 0;
  ushort_t* A1 = (ushort_t*)d_ws;
  ushort_t* A2 = A1 + 8388608;
  ushort_t* B1 = A2 + 8388608;
  ushort_t* B2 = B1 + 3 * BSLICE;
  float* partials = (float*)(B2 + 3 * BSLICE);

  k_pre_elem<<<N_PRE / 4 / 256, 256, 0, stream>>>(in_sp, tpre, o_trpre);
  k_post<<<N_POST / 8 / 256, 256, 0, stream>>>(out_sp, tpost, o_trpost, A1, A2, use_mfma);
  if (use_mfma) {
    k_bfill<<<540672 / 256, 256, 0, stream>>>(in_sp, tpre, B1, B2);
    dim3 g(64, 2, 9);
    k_mfma<<<g, 128, 0, stream>>>(A1, A2, B1, B2, partials);
    k_finalize<<<N_DW / 256, 256, 0, stream>>>(partials, weight, o_dw);
  } else {
    k_naive<<<N_DW / 256, 256, 0, stream>>>(out_sp, tpost, tpre, in_sp, weight, o_dw);
  }
}